// Round 1
// baseline (313.559 us; speedup 1.0000x reference)
//
#include <hip/hip_runtime.h>

// LocalLayer: y = x @ W^T + b, W is banded: output window k (16 outputs,
// o in [16k,16k+16)) reads only input cols [16k-32, 16k+32) (clamped to
// [0,4096)). Exploit: banded GEMM = 4.3 GFLOP (vs 275 dense) -> HBM-bound
// at ~295 MB total traffic (~47 us roofline).
//
// Kernel 1 packs banded W (bf16, zero-filled edges) in MFMA B-fragment
// order into d_ws (512 KB). Kernel 2: 64-row x 16-window blocks, x staged
// fp32->bf16 in LDS, 16x16x32 bf16 MFMA, bias folded into acc init.

typedef __attribute__((ext_vector_type(8))) short short8;
typedef __attribute__((ext_vector_type(4))) float f32x4;
typedef __attribute__((ext_vector_type(4))) unsigned short us4;

#define IN_F 4096
#define OUT_F 4096
#define NROWS 8192
#define ROWS 64                 // batch rows per block
#define GW 16                   // windows per block (256 output cols)
#define BAND (GW * 16 + 48)     // 304 input cols covered by a window group
#define LSTRIDE 312             // LDS row stride (bf16): 16B-aligned, stride_dw%8==4 -> 2-way (free)
#define V4 (BAND / 4)           // 76 float4 per staged row

__device__ __forceinline__ unsigned short f2bf(float f) {
  unsigned int u = __float_as_uint(f);
  u += 0x7FFFu + ((u >> 16) & 1u);   // round-to-nearest-even
  return (unsigned short)(u >> 16);
}

// Pack banded W into MFMA B-fragment order, bf16.
// Fragment f = win*2 + t (t = K-half). Lane: n = lane&15 (output col within
// window), quad = lane>>4, k = quad*8 + j. W column = win*16 - 32 + t*32 + k,
// zero outside [0, IN_F). Store at Wp[(f*64 + lane)*8 + j]  (== tid*8 + j).
__global__ void pack_w_kernel(const float* __restrict__ W,
                              unsigned short* __restrict__ Wp) {
  int tid = blockIdx.x * 256 + threadIdx.x;  // 32768 threads total
  int lane = tid & 63;
  int t = (tid >> 6) & 1;
  int win = tid >> 7;
  int n = lane & 15, quad = lane >> 4;
  int o = win * 16 + n;
  int cbase = win * 16 - 32 + t * 32 + quad * 8;
  short8 h;
#pragma unroll
  for (int j = 0; j < 8; ++j) {
    int c = cbase + j;
    float v = (c >= 0 && c < IN_F) ? W[o * IN_F + c] : 0.0f;
    h[j] = (short)f2bf(v);
  }
  *(short8*)(Wp + (size_t)tid * 8) = h;
}

__global__ __launch_bounds__(256) void local_gemm_kernel(
    const float* __restrict__ x, const unsigned short* __restrict__ Wp,
    const float* __restrict__ bias, float* __restrict__ out) {
  __shared__ unsigned short xs[ROWS * LSTRIDE];  // 39936 B
  const int tid = threadIdx.x;
  const int row0 = blockIdx.x * ROWS;
  const int wg = blockIdx.y;                 // window group (16 windows)
  const int colstart = wg * (GW * 16) - 32;  // may be <0 (wg=0) or run past 4096 (wg=15)

  // Stage x band: fp32 global -> bf16 LDS. Edge chunks are float4-aligned
  // in/out of range, zero-fill keeps NaN-free (packed W is 0 there anyway).
  for (int idx = tid; idx < ROWS * V4; idx += 256) {
    int r = idx / V4;
    int c4 = idx - r * V4;
    int gc = colstart + c4 * 4;
    float4 v = make_float4(0.f, 0.f, 0.f, 0.f);
    if (gc >= 0 && gc < IN_F)
      v = *(const float4*)(x + (row0 + r) * IN_F + gc);
    us4 h = {f2bf(v.x), f2bf(v.y), f2bf(v.z), f2bf(v.w)};
    *(us4*)(xs + r * LSTRIDE + c4 * 4) = h;
  }
  __syncthreads();

  const int lane = tid & 63;
  const int wave = tid >> 6;   // 4 waves: wave m-tiles of 16 rows
  const int n16 = lane & 15;
  const int quad = lane >> 4;
  const int mrow = wave * 16;

  f32x4 acc[GW];
#pragma unroll
  for (int w = 0; w < GW; ++w) {
    float bv = bias[wg * 256 + w * 16 + n16];  // bias is per output col
    acc[w] = (f32x4){bv, bv, bv, bv};
  }

  const short8* wpv = (const short8*)Wp;
  const unsigned short* xrow = xs + (mrow + n16) * LSTRIDE + quad * 8;
#pragma unroll
  for (int w = 0; w < GW; ++w) {
    int win = wg * GW + w;
    // B fragments: coalesced 16 B/lane, L2/L3-resident (512 KB total)
    short8 b0 = wpv[(win * 2 + 0) * 64 + lane];
    short8 b1 = wpv[(win * 2 + 1) * 64 + lane];
    // A fragments: ds_read_b128, window w band starts at local col w*16
    short8 a0 = *(const short8*)(xrow + w * 16);
    short8 a1 = *(const short8*)(xrow + w * 16 + 32);
    acc[w] = __builtin_amdgcn_mfma_f32_16x16x32_bf16(a0, b0, acc[w], 0, 0, 0);
    acc[w] = __builtin_amdgcn_mfma_f32_16x16x32_bf16(a1, b1, acc[w], 0, 0, 0);
  }

  // C/D layout: col = lane&15, row = quad*4 + reg  [m89]
  float* op = out + (size_t)(row0 + mrow + quad * 4) * OUT_F + wg * 256 + n16;
#pragma unroll
  for (int w = 0; w < GW; ++w) {
#pragma unroll
    for (int r = 0; r < 4; ++r) op[r * OUT_F + w * 16] = acc[w][r];
  }
}

extern "C" void kernel_launch(void* const* d_in, const int* in_sizes, int n_in,
                              void* d_out, int out_size, void* d_ws, size_t ws_size,
                              hipStream_t stream) {
  const float* x = (const float*)d_in[0];
  const float* W = (const float*)d_in[1];
  const float* b = (const float*)d_in[2];
  // d_in[3] = mask, unused (band structure is compile-time known)
  float* out = (float*)d_out;
  unsigned short* Wp = (unsigned short*)d_ws;  // 256*2*64*8*2 = 512 KB

  hipLaunchKernelGGL(pack_w_kernel, dim3(128), dim3(256), 0, stream, W, Wp);
  hipLaunchKernelGGL(local_gemm_kernel, dim3(NROWS / ROWS, 256 / GW), dim3(256),
                     0, stream, x, Wp, b, out);
}